// Round 1
// baseline (634.169 us; speedup 1.0000x reference)
//
#include <hip/hip_runtime.h>
#include <cstdint>
#include <cstddef>

// HRRRouter: scores = normalize( x @ (W^T @ Mc) ) @ E^T,  Mc[d,i]=R[(d-i)&2047]
// R[d] = sum_k sum_m E[k,m]*L[k,(d-m)&2047];  L,E row-normalized labels/signatures.
// Split-fp16 GEMMs (v = hi + lo/2048, lo prescaled into fp16 normal range) for
// ~fp32 accuracy; fp64 accumulation in the final scores reduction.

typedef _Float16 f16x8 __attribute__((ext_vector_type(8)));
typedef _Float16 f16x4 __attribute__((ext_vector_type(4)));
typedef float    f32x4 __attribute__((ext_vector_type(4)));

#define NROWS 16384
#define DDIM  2048
#define KEXP  8
#define IDX_OFF  (NROWS * 2)
#define SCR_OFF  (NROWS * 4)

__device__ __forceinline__ void gload16(const void* g, void* l) {
  __builtin_amdgcn_global_load_lds(
      (const __attribute__((address_space(1))) void*)g,
      (__attribute__((address_space(3))) void*)l, 16, 0, 0);
}

// ---------------- normalize labels & signatures ----------------
__global__ void k_norm(const float* __restrict__ lab, const float* __restrict__ sig,
                       float* __restrict__ Lb, float* __restrict__ Eb) {
  int b = blockIdx.x;
  const float* src = (b < KEXP) ? lab + (size_t)b * DDIM : sig + (size_t)(b - KEXP) * DDIM;
  float* dst       = (b < KEXP) ? Lb  + (size_t)b * DDIM : Eb  + (size_t)(b - KEXP) * DDIM;
  int t = threadIdx.x, lane = t & 63, w = t >> 6;
  double ss = 0.0;
  for (int i = t; i < DDIM; i += 256) { float v = src[i]; ss += (double)v * (double)v; }
#pragma unroll
  for (int o = 32; o; o >>= 1) ss += __shfl_down(ss, o);
  __shared__ double red[4];
  __shared__ float rns;
  if (lane == 0) red[w] = ss;
  __syncthreads();
  if (t == 0) {
    double tot = red[0] + red[1] + red[2] + red[3];
    double n = sqrt(tot); if (n < 1e-12) n = 1e-12;
    rns = (float)(1.0 / n);
  }
  __syncthreads();
  float rn = rns;
  for (int i = t; i < DDIM; i += 256) dst[i] = src[i] * rn;
}

// ---------------- R (circular conv sum), replicated to Rext[0..4111] ----------------
__global__ void k_R(const float* __restrict__ Lb, const float* __restrict__ Eb,
                    float* __restrict__ Rext) {
  int d = blockIdx.x;
  int t = threadIdx.x, lane = t & 63, w = t >> 6;
  double acc = 0.0;
  for (int idx = t; idx < KEXP * DDIM; idx += 256) {
    int k = idx >> 11, m = idx & 2047;
    acc += (double)Eb[(k << 11) + m] * (double)Lb[(k << 11) + ((d - m) & 2047)];
  }
#pragma unroll
  for (int o = 32; o; o >>= 1) acc += __shfl_down(acc, o);
  __shared__ double red[4];
  if (lane == 0) red[w] = acc;
  __syncthreads();
  if (t == 0) {
    float r = (float)(red[0] + red[1] + red[2] + red[3]);
    Rext[d] = r; Rext[d + 2048] = r;
    if (d < 16) Rext[d + 4096] = r;
  }
}

// ---------------- W [D,H] -> transposed split W_t[h][d] hi/lo fp16 ----------------
__global__ void k_wt(const float* __restrict__ W, _Float16* __restrict__ Wth,
                     _Float16* __restrict__ Wtl) {
  __shared__ float tl[32][33];
  int hb = blockIdx.x * 32, db = blockIdx.y * 32;
  int tx = threadIdx.x, ty = threadIdx.y;  // (32,8)
#pragma unroll
  for (int r = 0; r < 4; ++r) {
    int dd = ty + r * 8;
    tl[dd][tx] = W[(size_t)(db + dd) * DDIM + hb + tx];
  }
  __syncthreads();
#pragma unroll
  for (int r = 0; r < 4; ++r) {
    int hh = ty + r * 8;
    float v = tl[tx][hh];
    _Float16 hi = (_Float16)v;
    _Float16 lo = (_Float16)((v - (float)hi) * 2048.0f);
    size_t o = (size_t)(hb + hh) * DDIM + db + tx;
    Wth[o] = hi; Wtl[o] = lo;
  }
}

// ---------------- Mc_t[i][d] = R[(d-i)&2047] split fp16 ----------------
__global__ void k_mc(const float* __restrict__ Rext, _Float16* __restrict__ Mh,
                     _Float16* __restrict__ Ml) {
  int gid = blockIdx.x * 256 + threadIdx.x;   // 2048*256 threads
  int i  = gid >> 8;
  int j8 = (gid & 255) << 3;
  int base = (j8 - i) & 2047;
  f16x8 h8, l8;
#pragma unroll
  for (int e = 0; e < 8; ++e) {
    float v = Rext[base + e];
    _Float16 hi = (_Float16)v;
    h8[e] = hi;
    l8[e] = (_Float16)((v - (float)hi) * 2048.0f);
  }
  size_t o = (size_t)i * DDIM + j8;
  *(f16x8*)(Mh + o) = h8;
  *(f16x8*)(Ml + o) = l8;
}

// ---------------- x chunk f32 -> split fp16 ----------------
__global__ void k_xsplit(const float* __restrict__ x, _Float16* __restrict__ xh,
                         _Float16* __restrict__ xl, int n8) {
  int stride = gridDim.x * blockDim.x;
  for (int g = blockIdx.x * blockDim.x + threadIdx.x; g < n8; g += stride) {
    size_t o = (size_t)g * 8;
    float4 a = *(const float4*)(x + o);
    float4 b = *(const float4*)(x + o + 4);
    float va[8] = {a.x, a.y, a.z, a.w, b.x, b.y, b.z, b.w};
    f16x8 h8, l8;
#pragma unroll
    for (int j = 0; j < 8; ++j) {
      float v = va[j];
      _Float16 hi = (_Float16)v;
      h8[j] = hi;
      l8[j] = (_Float16)((v - (float)hi) * 2048.0f);
    }
    *(f16x8*)(xh + o) = h8;
    *(f16x8*)(xl + o) = l8;
  }
}

// ---------------- split-fp16 GEMM: C[m,n] = sum_k A[m,k]*B[n,k] ----------------
// EPI 0: write f32 C[M][N].  EPI 1: write transposed split fp16 Ch/Cl[n][m].
template <int EPI>
__global__ __launch_bounds__(256, 2)
void k_gemm(const _Float16* __restrict__ Ah, const _Float16* __restrict__ Al,
            const _Float16* __restrict__ Bh, const _Float16* __restrict__ Bl,
            float* __restrict__ Cf, _Float16* __restrict__ Ch,
            _Float16* __restrict__ Cl, int M, int N, int K) {
  __shared__ __align__(16) _Float16 sAh[128 * 32];
  __shared__ __align__(16) _Float16 sAl[128 * 32];
  __shared__ __align__(16) _Float16 sBh[128 * 32];
  __shared__ __align__(16) _Float16 sBl[128 * 32];

  const int tid = threadIdx.x;
  const int lane = tid & 63;
  const int wid = tid >> 6;
  const int wm = wid >> 1, wn = wid & 1;
  const int m0 = blockIdx.y * 128, n0 = blockIdx.x * 128;

  const int r0 = tid >> 2;            // staging row 0..63
  const int c0 = (tid & 3) * 8;       // staging k offset (halves)
  const int ldsOff0 = r0 * 32 + c0;
  const int ldsOff1 = (64 + r0) * 32 + c0;

  f32x4 acc0[4][4] = {};
  f32x4 acc1[4][4] = {};

  const int fr = lane & 15;
  const int fk = (lane >> 4) * 8;

  for (int kt = 0; kt < K; kt += 32) {
    const size_t ga0 = (size_t)(m0 + r0) * K + kt + c0;
    const size_t ga1 = ga0 + (size_t)64 * K;
    const size_t gb0 = (size_t)(n0 + r0) * K + kt + c0;
    const size_t gb1 = gb0 + (size_t)64 * K;
    gload16(Ah + ga0, sAh + ldsOff0);
    gload16(Ah + ga1, sAh + ldsOff1);
    gload16(Al + ga0, sAl + ldsOff0);
    gload16(Al + ga1, sAl + ldsOff1);
    gload16(Bh + gb0, sBh + ldsOff0);
    gload16(Bh + gb1, sBh + ldsOff1);
    gload16(Bl + gb0, sBl + ldsOff0);
    gload16(Bl + gb1, sBl + ldsOff1);
    __syncthreads();

    f16x8 ah[4], al[4], bh[4], bl[4];
#pragma unroll
    for (int i = 0; i < 4; ++i) {
      const int ao = (wm * 64 + i * 16 + fr) * 32 + fk;
      const int bo = (wn * 64 + i * 16 + fr) * 32 + fk;
      ah[i] = *(const f16x8*)(sAh + ao);
      al[i] = *(const f16x8*)(sAl + ao);
      bh[i] = *(const f16x8*)(sBh + bo);
      bl[i] = *(const f16x8*)(sBl + bo);
    }
#pragma unroll
    for (int mi = 0; mi < 4; ++mi)
#pragma unroll
      for (int ni = 0; ni < 4; ++ni) {
        acc0[mi][ni] = __builtin_amdgcn_mfma_f32_16x16x32_f16(ah[mi], bh[ni], acc0[mi][ni], 0, 0, 0);
        acc1[mi][ni] = __builtin_amdgcn_mfma_f32_16x16x32_f16(ah[mi], bl[ni], acc1[mi][ni], 0, 0, 0);
        acc1[mi][ni] = __builtin_amdgcn_mfma_f32_16x16x32_f16(al[mi], bh[ni], acc1[mi][ni], 0, 0, 0);
      }
    __syncthreads();
  }

  const float SC = 1.0f / 2048.0f;
  const int fq = lane >> 4;
#pragma unroll
  for (int mi = 0; mi < 4; ++mi)
#pragma unroll
    for (int ni = 0; ni < 4; ++ni) {
      float v[4];
#pragma unroll
      for (int j = 0; j < 4; ++j) v[j] = acc0[mi][ni][j] + acc1[mi][ni][j] * SC;
      if (EPI == 0) {
        const int row = m0 + wm * 64 + mi * 16 + fq * 4;
        const int col = n0 + wn * 64 + ni * 16 + fr;
#pragma unroll
        for (int j = 0; j < 4; ++j) Cf[(size_t)(row + j) * N + col] = v[j];
      } else {
        const int orow = n0 + wn * 64 + ni * 16 + fr;
        const int ocol = m0 + wm * 64 + mi * 16 + fq * 4;
        f16x4 h4, l4;
#pragma unroll
        for (int j = 0; j < 4; ++j) {
          _Float16 hh = (_Float16)v[j];
          h4[j] = hh;
          l4[j] = (_Float16)((v[j] - (float)hh) * 2048.0f);
        }
        *(f16x4*)(Ch + (size_t)orow * M + ocol) = h4;
        *(f16x4*)(Cl + (size_t)orow * M + ocol) = l4;
      }
    }
}

// ---------------- scores + top2 + softmax ----------------
__global__ void k_scores(const float* __restrict__ S, const float* __restrict__ Eb,
                         float* __restrict__ out, int rowbase) {
  int wid = threadIdx.x >> 6, lane = threadIdx.x & 63;
  int r = blockIdx.x * 4 + wid;
  const float* s = S + (size_t)r * DDIM;
  double nrm = 0.0, dk[8] = {0, 0, 0, 0, 0, 0, 0, 0};
  for (int i = lane; i < DDIM; i += 64) {
    float sv = s[i];
    nrm += (double)sv * (double)sv;
#pragma unroll
    for (int k = 0; k < 8; ++k) dk[k] += (double)sv * (double)Eb[k * DDIM + i];
  }
#pragma unroll
  for (int o = 32; o; o >>= 1) {
    nrm += __shfl_down(nrm, o);
#pragma unroll
    for (int k = 0; k < 8; ++k) dk[k] += __shfl_down(dk[k], o);
  }
  if (lane == 0) {
    double nn = sqrt(nrm); if (nn < 1e-12) nn = 1e-12;
    float sc[8];
#pragma unroll
    for (int k = 0; k < 8; ++k) sc[k] = (float)(dk[k] / nn);
    float v1 = -3.4e38f, v2 = -3.4e38f; int i1 = 0, i2 = 0;
#pragma unroll
    for (int k = 0; k < 8; ++k) {
      float v = sc[k];
      if (v > v1) { v2 = v1; i2 = i1; v1 = v; i1 = k; }
      else if (v > v2) { v2 = v; i2 = k; }
    }
    float e = expf(v2 - v1);
    float w1 = 1.0f / (1.0f + e);
    float w2 = e / (1.0f + e);
    int gr = rowbase + r;
    out[(size_t)gr * 2] = w1;
    out[(size_t)gr * 2 + 1] = w2;
    out[IDX_OFF + (size_t)gr * 2] = (float)i1;
    out[IDX_OFF + (size_t)gr * 2 + 1] = (float)i2;
#pragma unroll
    for (int k = 0; k < 8; ++k) out[SCR_OFF + (size_t)gr * 8 + k] = sc[k];
  }
}

extern "C" void kernel_launch(void* const* d_in, const int* in_sizes, int n_in,
                              void* d_out, int out_size, void* d_ws, size_t ws_size,
                              hipStream_t stream) {
  const float* x   = (const float*)d_in[0];
  const float* W   = (const float*)d_in[1];
  const float* lab = (const float*)d_in[2];
  const float* sig = (const float*)d_in[3];
  float* out = (float*)d_out;

  // workspace carve
  char* p = (char*)d_ws;
  auto alloc = [&](size_t bytes) {
    void* r = (void*)p;
    p += (bytes + 255) & ~(size_t)255;
    return r;
  };
  float* Lb   = (float*)alloc((size_t)KEXP * DDIM * 4);
  float* Eb   = (float*)alloc((size_t)KEXP * DDIM * 4);
  float* Rext = (float*)alloc((size_t)4112 * 4);
  _Float16* Wth = (_Float16*)alloc((size_t)DDIM * DDIM * 2);
  _Float16* Wtl = (_Float16*)alloc((size_t)DDIM * DDIM * 2);
  _Float16* Mch = (_Float16*)alloc((size_t)DDIM * DDIM * 2);
  _Float16* Mcl = (_Float16*)alloc((size_t)DDIM * DDIM * 2);
  _Float16* Ath = (_Float16*)alloc((size_t)DDIM * DDIM * 2);
  _Float16* Atl = (_Float16*)alloc((size_t)DDIM * DDIM * 2);
  size_t fixed = (size_t)(p - (char*)d_ws);

  int NC = NROWS;  // chunk rows; shrink until workspace fits
  while (NC > 128 && fixed + (size_t)NC * 16384 + 4096 > ws_size) NC >>= 1;
  _Float16* Xch = (_Float16*)alloc((size_t)NC * DDIM * 2);
  _Float16* Xcl = (_Float16*)alloc((size_t)NC * DDIM * 2);
  float*    Sc  = (float*)alloc((size_t)NC * DDIM * 4);

  k_norm<<<16, 256, 0, stream>>>(lab, sig, Lb, Eb);
  k_R<<<2048, 256, 0, stream>>>(Lb, Eb, Rext);
  k_wt<<<dim3(64, 64), dim3(32, 8), 0, stream>>>(W, Wth, Wtl);
  k_mc<<<2048, 256, 0, stream>>>(Rext, Mch, Mcl);
  // A_t[i][h] = sum_d W_t[h,d] * Mc_t[i,d]  (written transposed, split fp16)
  k_gemm<1><<<dim3(16, 16), 256, 0, stream>>>(Wth, Wtl, Mch, Mcl, nullptr, Ath, Atl,
                                              DDIM, DDIM, DDIM);
  const int nchunks = NROWS / NC;
  for (int c = 0; c < nchunks; ++c) {
    const float* xc = x + (size_t)c * NC * DDIM;
    k_xsplit<<<1024, 256, 0, stream>>>(xc, Xch, Xcl, NC * DDIM / 8);
    k_gemm<0><<<dim3(16, NC / 128), 256, 0, stream>>>(Xch, Xcl, Ath, Atl, Sc, nullptr,
                                                      nullptr, NC, DDIM, DDIM);
    k_scores<<<NC / 4, 256, 0, stream>>>(Sc, Eb, out, c * NC);
  }
}

// Round 2
// 458.923 us; speedup vs baseline: 1.3819x; 1.3819x over previous
//
#include <hip/hip_runtime.h>
#include <cstdint>
#include <cstddef>

// HRRRouter restructured:
//   scores[n,k] = numer[n,k] / ||x_n @ A||,  A = W^T @ Mc,  Mc[d,i]=R[(d-i)&2047]
//   numer = x @ B,  B[h,k] = sum_d W[d,h] * F2[d,k],  F2[d,k] = sum_i R[(d-i)&2047]E[k,i]
// Norm path is scale-uniform per row -> plain fp16 single-MFMA GEMM suffices.
// Numerator path is fp64-accumulated off fp32 x -> index ordering exact.

typedef _Float16 f16x8 __attribute__((ext_vector_type(8)));
typedef _Float16 f16x4 __attribute__((ext_vector_type(4)));
typedef float    f32x4 __attribute__((ext_vector_type(4)));

#define NROWS 16384
#define DDIM  2048
#define KEXP  8
#define IDX_OFF  (NROWS * 2)
#define SCR_OFF  (NROWS * 4)

__device__ __forceinline__ void gload16(const void* g, void* l) {
  __builtin_amdgcn_global_load_lds(
      (const __attribute__((address_space(1))) void*)g,
      (__attribute__((address_space(3))) void*)l, 16, 0, 0);
}

// ---------------- normalize labels & signatures ----------------
__global__ void k_norm(const float* __restrict__ lab, const float* __restrict__ sig,
                       float* __restrict__ Lb, float* __restrict__ Eb) {
  int b = blockIdx.x;
  const float* src = (b < KEXP) ? lab + (size_t)b * DDIM : sig + (size_t)(b - KEXP) * DDIM;
  float* dst       = (b < KEXP) ? Lb  + (size_t)b * DDIM : Eb  + (size_t)(b - KEXP) * DDIM;
  int t = threadIdx.x, lane = t & 63, w = t >> 6;
  double ss = 0.0;
  for (int i = t; i < DDIM; i += 256) { float v = src[i]; ss += (double)v * (double)v; }
#pragma unroll
  for (int o = 32; o; o >>= 1) ss += __shfl_down(ss, o);
  __shared__ double red[4];
  __shared__ float rns;
  if (lane == 0) red[w] = ss;
  __syncthreads();
  if (t == 0) {
    double tot = red[0] + red[1] + red[2] + red[3];
    double n = sqrt(tot); if (n < 1e-12) n = 1e-12;
    rns = (float)(1.0 / n);
  }
  __syncthreads();
  float rn = rns;
  for (int i = t; i < DDIM; i += 256) dst[i] = src[i] * rn;
}

// ---------------- R (circular conv sum), replicated to Rext[0..4111] ----------------
__global__ void k_R(const float* __restrict__ Lb, const float* __restrict__ Eb,
                    float* __restrict__ Rext) {
  int d = blockIdx.x;
  int t = threadIdx.x, lane = t & 63, w = t >> 6;
  double acc = 0.0;
  for (int idx = t; idx < KEXP * DDIM; idx += 256) {
    int k = idx >> 11, m = idx & 2047;
    acc += (double)Eb[(k << 11) + m] * (double)Lb[(k << 11) + ((d - m) & 2047)];
  }
#pragma unroll
  for (int o = 32; o; o >>= 1) acc += __shfl_down(acc, o);
  __shared__ double red[4];
  if (lane == 0) red[w] = acc;
  __syncthreads();
  if (t == 0) {
    float r = (float)(red[0] + red[1] + red[2] + red[3]);
    Rext[d] = r; Rext[d + 2048] = r;
    if (d < 16) Rext[d + 4096] = r;
  }
}

// ---------------- F2[d,k] = sum_i R[(d-i)&2047] * E[k,i]  (fp64 accum) -------------
__global__ void k_F2(const float* __restrict__ Rext, const float* __restrict__ Eb,
                     float* __restrict__ F2) {
  int d = blockIdx.x;
  int t = threadIdx.x, lane = t & 63, w = t >> 6;
  double acc[KEXP] = {};
  for (int i = t; i < DDIM; i += 256) {
    double rv = (double)Rext[(d - i) & 2047];
#pragma unroll
    for (int k = 0; k < KEXP; ++k) acc[k] += rv * (double)Eb[(k << 11) + i];
  }
#pragma unroll
  for (int o = 32; o; o >>= 1)
#pragma unroll
    for (int k = 0; k < KEXP; ++k) acc[k] += __shfl_down(acc[k], o);
  __shared__ double red[4][KEXP];
  if (lane == 0)
#pragma unroll
    for (int k = 0; k < KEXP; ++k) red[w][k] = acc[k];
  __syncthreads();
  if (t < KEXP) {
    double s = red[0][t] + red[1][t] + red[2][t] + red[3][t];
    F2[(size_t)d * KEXP + t] = (float)s;
  }
}

// ---------------- B[h,k] = sum_d W[d,h] * F2[d,k]  (fp64 accum) ----------------
__global__ void k_B(const float* __restrict__ W, const float* __restrict__ F2,
                    float* __restrict__ Bm) {
  int h0 = blockIdx.x * 64;
  int t = threadIdx.x, hl = t & 63, ds = t >> 6;
  int h = h0 + hl;
  double acc[KEXP] = {};
  for (int d = ds; d < DDIM; d += 4) {
    double wv = (double)W[(size_t)d * DDIM + h];
#pragma unroll
    for (int k = 0; k < KEXP; ++k) acc[k] += wv * (double)F2[(size_t)d * KEXP + k];
  }
  __shared__ double sacc[4][64][KEXP];
#pragma unroll
  for (int k = 0; k < KEXP; ++k) sacc[ds][hl][k] = acc[k];
  __syncthreads();
  if (t < 64) {
#pragma unroll
    for (int k = 0; k < KEXP; ++k) {
      double s = sacc[0][t][k] + sacc[1][t][k] + sacc[2][t][k] + sacc[3][t][k];
      Bm[(size_t)(h0 + t) * KEXP + k] = (float)s;
    }
  }
}

// ---------------- W [D,H] -> transposed fp16 Wth[h][d] ----------------
__global__ void k_wt(const float* __restrict__ W, _Float16* __restrict__ Wth) {
  __shared__ float tl[32][33];
  int hb = blockIdx.x * 32, db = blockIdx.y * 32;
  int tx = threadIdx.x, ty = threadIdx.y;  // (32,8)
#pragma unroll
  for (int r = 0; r < 4; ++r) {
    int dd = ty + r * 8;
    tl[dd][tx] = W[(size_t)(db + dd) * DDIM + hb + tx];
  }
  __syncthreads();
#pragma unroll
  for (int r = 0; r < 4; ++r) {
    int hh = ty + r * 8;
    Wth[(size_t)(hb + hh) * DDIM + db + tx] = (_Float16)tl[tx][hh];
  }
}

// ---------------- Mct[i][d] = fp16(R[(d-i)&2047]) ----------------
__global__ void k_mc(const float* __restrict__ Rext, _Float16* __restrict__ Mct) {
  int gid = blockIdx.x * 256 + threadIdx.x;
  int i  = gid >> 8;
  int j8 = (gid & 255) << 3;
  int base = (j8 - i) & 2047;
  f16x8 h8;
#pragma unroll
  for (int e = 0; e < 8; ++e) h8[e] = (_Float16)Rext[base + e];
  *(f16x8*)(Mct + (size_t)i * DDIM + j8) = h8;
}

// ---------------- x chunk f32 -> fp16 ----------------
__global__ void k_xh(const float* __restrict__ x, _Float16* __restrict__ xh, int n8) {
  int stride = gridDim.x * blockDim.x;
  for (int g = blockIdx.x * blockDim.x + threadIdx.x; g < n8; g += stride) {
    size_t o = (size_t)g * 8;
    float4 a = *(const float4*)(x + o);
    float4 b = *(const float4*)(x + o + 4);
    f16x8 h8;
    h8[0] = (_Float16)a.x; h8[1] = (_Float16)a.y;
    h8[2] = (_Float16)a.z; h8[3] = (_Float16)a.w;
    h8[4] = (_Float16)b.x; h8[5] = (_Float16)b.y;
    h8[6] = (_Float16)b.z; h8[7] = (_Float16)b.w;
    *(f16x8*)(xh + o) = h8;
  }
}

// ---------------- fp16 GEMM, BK=64, XOR-swizzled LDS ----------------
// C[m,n] = sum_k A[m,k]*B[n,k]
// EPI 0: per-row sum of squares -> Pn[bx][rowbase + m]   (norm path)
// EPI 1: Ct[n][m] = fp16(C[m,n])                          (A_t build)
template <int EPI>
__global__ __launch_bounds__(256, 2)
void k_gemm16(const _Float16* __restrict__ A, const _Float16* __restrict__ B,
              float* __restrict__ Pn, _Float16* __restrict__ Ct,
              int M, int N, int K, int rowbase, int Mtot) {
  __shared__ __align__(16) _Float16 sA[128 * 64];
  __shared__ __align__(16) _Float16 sB[128 * 64];
  __shared__ float sred[2][2][64];

  const int nbx = N >> 7;
  const int nwg = gridDim.x * gridDim.y;
  const int lin = blockIdx.y * gridDim.x + blockIdx.x;
  // m204 bijective XCD swizzle
  const int qq = nwg >> 3, rr = nwg & 7;
  const int xcd = lin & 7, pos = lin >> 3;
  const int swz = ((xcd < rr) ? xcd * (qq + 1) : rr * (qq + 1) + (xcd - rr) * qq) + pos;
  const int bx = swz % nbx, by = swz / nbx;

  const int tid = threadIdx.x;
  const int lane = tid & 63;
  const int wid = tid >> 6;
  const int wm = wid >> 1, wn = wid & 1;
  const int m0 = by * 128, n0 = bx * 128;
  const int fr = lane & 15, fq = lane >> 4;

  f32x4 acc[4][4] = {};

  for (int kt = 0; kt < K; kt += 64) {
#pragma unroll
    for (int p = 0; p < 4; ++p) {
      int s = p * 256 + tid;      // 16B slot in buffer
      int r = s >> 3, c = s & 7;  // row, slot-in-row
      int ks = (c ^ (r & 7)) << 3;  // inverse-swizzled global k (halves)
      gload16(A + (size_t)(m0 + r) * K + kt + ks, (char*)sA + (size_t)s * 16);
      gload16(B + (size_t)(n0 + r) * K + kt + ks, (char*)sB + (size_t)s * 16);
    }
    __syncthreads();
#pragma unroll
    for (int kk = 0; kk < 2; ++kk) {
      f16x8 av[4], bv[4];
      const int q = (kk << 2) + fq;
#pragma unroll
      for (int i = 0; i < 4; ++i) {
        const int Ra = wm * 64 + i * 16 + fr;
        const int Rb = wn * 64 + i * 16 + fr;
        av[i] = *(const f16x8*)((char*)sA + Ra * 128 + ((q ^ (Ra & 7)) << 4));
        bv[i] = *(const f16x8*)((char*)sB + Rb * 128 + ((q ^ (Rb & 7)) << 4));
      }
#pragma unroll
      for (int mi = 0; mi < 4; ++mi)
#pragma unroll
        for (int ni = 0; ni < 4; ++ni)
          acc[mi][ni] = __builtin_amdgcn_mfma_f32_16x16x32_f16(av[mi], bv[ni], acc[mi][ni], 0, 0, 0);
    }
    __syncthreads();
  }

  if (EPI == 0) {
    // per-row sum of squares over this block's 128 cols
#pragma unroll
    for (int mi = 0; mi < 4; ++mi)
#pragma unroll
      for (int j = 0; j < 4; ++j) {
        float s = 0.f;
#pragma unroll
        for (int ni = 0; ni < 4; ++ni) s += acc[mi][ni][j] * acc[mi][ni][j];
#pragma unroll
        for (int o = 1; o < 16; o <<= 1) s += __shfl_xor(s, o);
        if (fr == 0) sred[wm][wn][mi * 16 + fq * 4 + j] = s;
      }
    __syncthreads();
    if (tid < 128) {
      int wmm = tid >> 6, rl = tid & 63;
      float v = sred[wmm][0][rl] + sred[wmm][1][rl];
      Pn[(size_t)bx * NROWS + rowbase + m0 + wmm * 64 + rl] = v;
    }
  } else {
#pragma unroll
    for (int mi = 0; mi < 4; ++mi)
#pragma unroll
      for (int ni = 0; ni < 4; ++ni) {
        const int orow = n0 + wn * 64 + ni * 16 + fr;
        const int ocol = m0 + wm * 64 + mi * 16 + fq * 4;
        f16x4 h4;
#pragma unroll
        for (int j = 0; j < 4; ++j) h4[j] = (_Float16)acc[mi][ni][j];
        *(f16x4*)(Ct + (size_t)orow * Mtot + ocol) = h4;
      }
  }
}

// ---------------- numerator + norm + top2 + softmax ----------------
__global__ void k_scores(const float* __restrict__ x, const float* __restrict__ Bm,
                         const float* __restrict__ Pn, float* __restrict__ out,
                         int rowbase) {
  int wid = threadIdx.x >> 6, lane = threadIdx.x & 63;
  int r = rowbase + blockIdx.x * 4 + wid;
  const float* xr = x + (size_t)r * DDIM;
  double dk[KEXP] = {};
  for (int h = lane; h < DDIM; h += 64) {
    double xv = (double)xr[h];
    const float4* bp = (const float4*)(Bm + (size_t)h * KEXP);
    float4 b0 = bp[0], b1 = bp[1];
    dk[0] += xv * b0.x; dk[1] += xv * b0.y; dk[2] += xv * b0.z; dk[3] += xv * b0.w;
    dk[4] += xv * b1.x; dk[5] += xv * b1.y; dk[6] += xv * b1.z; dk[7] += xv * b1.w;
  }
#pragma unroll
  for (int o = 32; o; o >>= 1)
#pragma unroll
    for (int k = 0; k < KEXP; ++k) dk[k] += __shfl_down(dk[k], o);
  if (lane == 0) {
    double ns = 0.0;
#pragma unroll
    for (int b = 0; b < 16; ++b) ns += (double)Pn[(size_t)b * NROWS + r];
    double nn = sqrt(ns); if (nn < 1e-12) nn = 1e-12;
    float sc[KEXP];
#pragma unroll
    for (int k = 0; k < KEXP; ++k) sc[k] = (float)(dk[k] / nn);
    float v1 = -3.4e38f, v2 = -3.4e38f; int i1 = 0, i2 = 0;
#pragma unroll
    for (int k = 0; k < KEXP; ++k) {
      float v = sc[k];
      if (v > v1) { v2 = v1; i2 = i1; v1 = v; i1 = k; }
      else if (v > v2) { v2 = v; i2 = k; }
    }
    float e = expf(v2 - v1);
    float w1 = 1.0f / (1.0f + e);
    float w2 = e / (1.0f + e);
    out[(size_t)r * 2] = w1;
    out[(size_t)r * 2 + 1] = w2;
    out[IDX_OFF + (size_t)r * 2] = (float)i1;
    out[IDX_OFF + (size_t)r * 2 + 1] = (float)i2;
#pragma unroll
    for (int k = 0; k < KEXP; ++k) out[SCR_OFF + (size_t)r * 8 + k] = sc[k];
  }
}

extern "C" void kernel_launch(void* const* d_in, const int* in_sizes, int n_in,
                              void* d_out, int out_size, void* d_ws, size_t ws_size,
                              hipStream_t stream) {
  const float* x   = (const float*)d_in[0];
  const float* W   = (const float*)d_in[1];
  const float* lab = (const float*)d_in[2];
  const float* sig = (const float*)d_in[3];
  float* out = (float*)d_out;

  char* p = (char*)d_ws;
  auto alloc = [&](size_t bytes) {
    void* r = (void*)p;
    p += (bytes + 255) & ~(size_t)255;
    return r;
  };
  float* Lb   = (float*)alloc((size_t)KEXP * DDIM * 4);
  float* Eb   = (float*)alloc((size_t)KEXP * DDIM * 4);
  float* Rext = (float*)alloc((size_t)4112 * 4);
  float* F2   = (float*)alloc((size_t)DDIM * KEXP * 4);
  float* Bm   = (float*)alloc((size_t)DDIM * KEXP * 4);
  _Float16* Wth = (_Float16*)alloc((size_t)DDIM * DDIM * 2);
  _Float16* Mct = (_Float16*)alloc((size_t)DDIM * DDIM * 2);
  _Float16* At  = (_Float16*)alloc((size_t)DDIM * DDIM * 2);
  float* Pn     = (float*)alloc((size_t)16 * NROWS * 4);
  size_t fixed = (size_t)(p - (char*)d_ws);

  int NC = NROWS;  // xh chunk rows
  while (NC > 2048 && fixed + (size_t)NC * DDIM * 2 + 4096 > ws_size) NC >>= 1;
  _Float16* Xh = (_Float16*)alloc((size_t)NC * DDIM * 2);

  k_norm<<<16, 256, 0, stream>>>(lab, sig, Lb, Eb);
  k_R<<<2048, 256, 0, stream>>>(Lb, Eb, Rext);
  k_F2<<<2048, 256, 0, stream>>>(Rext, Eb, F2);
  k_B<<<32, 256, 0, stream>>>(W, F2, Bm);
  k_wt<<<dim3(64, 64), dim3(32, 8), 0, stream>>>(W, Wth);
  k_mc<<<2048, 256, 0, stream>>>(Rext, Mct);
  // At[i][h] = fp16( sum_d Wth[h,d] * Mct[i,d] )
  k_gemm16<1><<<dim3(16, 16), 256, 0, stream>>>(Wth, Mct, nullptr, At,
                                                DDIM, DDIM, DDIM, 0, DDIM);
  const int nchunks = NROWS / NC;
  for (int c = 0; c < nchunks; ++c) {
    const float* xc = x + (size_t)c * NC * DDIM;
    k_xh<<<1024, 256, 0, stream>>>(xc, Xh, NC * DDIM / 8);
    k_gemm16<0><<<dim3(16, NC / 128), 256, 0, stream>>>(Xh, At, Pn, nullptr,
                                                        NC, DDIM, DDIM, c * NC, DDIM);
    k_scores<<<NC / 4, 256, 0, stream>>>(x, Bm, Pn, out, c * NC);
  }
}

// Round 3
// 298.744 us; speedup vs baseline: 2.1228x; 1.5362x over previous
//
#include <hip/hip_runtime.h>
#include <cstdint>
#include <cstddef>

// HRRRouter restructured:
//   scores[n,k] = numer[n,k] / ||x_n @ A||,  A = W^T @ Mc,  Mc[d,i]=R[(d-i)&2047]
//   numer = x @ B,  B[h,k] = sum_d W[d,h] * F2[d,k],  F2[d,k] = sum_i R[(d-i)&2047]E[k,i]
// Norm path is scale-uniform per row -> plain fp16 single-MFMA GEMM suffices.
// Numerator path is fp64-accumulated off fp32 x -> index ordering exact.

typedef _Float16 f16x8 __attribute__((ext_vector_type(8)));
typedef _Float16 f16x4 __attribute__((ext_vector_type(4)));
typedef float    f32x4 __attribute__((ext_vector_type(4)));

#define NROWS 16384
#define DDIM  2048
#define KEXP  8
#define IDX_OFF  (NROWS * 2)
#define SCR_OFF  (NROWS * 4)

__device__ __forceinline__ void gload16(const void* g, void* l) {
  __builtin_amdgcn_global_load_lds(
      (const __attribute__((address_space(1))) void*)g,
      (__attribute__((address_space(3))) void*)l, 16, 0, 0);
}

// ---------------- normalize labels & signatures ----------------
__global__ void k_norm(const float* __restrict__ lab, const float* __restrict__ sig,
                       float* __restrict__ Lb, float* __restrict__ Eb) {
  int b = blockIdx.x;
  const float* src = (b < KEXP) ? lab + (size_t)b * DDIM : sig + (size_t)(b - KEXP) * DDIM;
  float* dst       = (b < KEXP) ? Lb  + (size_t)b * DDIM : Eb  + (size_t)(b - KEXP) * DDIM;
  int t = threadIdx.x, lane = t & 63, w = t >> 6;
  double ss = 0.0;
  for (int i = t; i < DDIM; i += 256) { float v = src[i]; ss += (double)v * (double)v; }
#pragma unroll
  for (int o = 32; o; o >>= 1) ss += __shfl_down(ss, o);
  __shared__ double red[4];
  __shared__ float rns;
  if (lane == 0) red[w] = ss;
  __syncthreads();
  if (t == 0) {
    double tot = red[0] + red[1] + red[2] + red[3];
    double n = sqrt(tot); if (n < 1e-12) n = 1e-12;
    rns = (float)(1.0 / n);
  }
  __syncthreads();
  float rn = rns;
  for (int i = t; i < DDIM; i += 256) dst[i] = src[i] * rn;
}

// ---------------- R (circular conv sum), replicated to Rext[0..4111] ----------------
__global__ void k_R(const float* __restrict__ Lb, const float* __restrict__ Eb,
                    float* __restrict__ Rext) {
  int d = blockIdx.x;
  int t = threadIdx.x, lane = t & 63, w = t >> 6;
  double acc = 0.0;
  for (int idx = t; idx < KEXP * DDIM; idx += 256) {
    int k = idx >> 11, m = idx & 2047;
    acc += (double)Eb[(k << 11) + m] * (double)Lb[(k << 11) + ((d - m) & 2047)];
  }
#pragma unroll
  for (int o = 32; o; o >>= 1) acc += __shfl_down(acc, o);
  __shared__ double red[4];
  if (lane == 0) red[w] = acc;
  __syncthreads();
  if (t == 0) {
    float r = (float)(red[0] + red[1] + red[2] + red[3]);
    Rext[d] = r; Rext[d + 2048] = r;
    if (d < 16) Rext[d + 4096] = r;
  }
}

// ---------------- F2[d,k] = sum_i R[(d-i)&2047] * E[k,i]  (fp64 accum) -------------
__global__ void k_F2(const float* __restrict__ Rext, const float* __restrict__ Eb,
                     float* __restrict__ F2) {
  int d = blockIdx.x;
  int t = threadIdx.x, lane = t & 63, w = t >> 6;
  double acc[KEXP] = {};
  for (int i = t; i < DDIM; i += 256) {
    double rv = (double)Rext[(d - i) & 2047];
#pragma unroll
    for (int k = 0; k < KEXP; ++k) acc[k] += rv * (double)Eb[(k << 11) + i];
  }
#pragma unroll
  for (int o = 32; o; o >>= 1)
#pragma unroll
    for (int k = 0; k < KEXP; ++k) acc[k] += __shfl_down(acc[k], o);
  __shared__ double red[4][KEXP];
  if (lane == 0)
#pragma unroll
    for (int k = 0; k < KEXP; ++k) red[w][k] = acc[k];
  __syncthreads();
  if (t < KEXP) {
    double s = red[0][t] + red[1][t] + red[2][t] + red[3][t];
    F2[(size_t)d * KEXP + t] = (float)s;
  }
}

// ---------------- B partials: Bp[db][h][k] = sum_{d in block} W[d,h]*F2[d,k] --------
__global__ void k_Bp(const float* __restrict__ W, const float* __restrict__ F2,
                     double* __restrict__ Bp) {
  int h0 = blockIdx.x * 64, d0 = blockIdx.y * 64;
  int t = threadIdx.x, hl = t & 63, ds = t >> 6;
  int h = h0 + hl;
  double acc[KEXP] = {};
#pragma unroll 4
  for (int d = d0 + ds; d < d0 + 64; d += 4) {
    double wv = (double)W[(size_t)d * DDIM + h];
    const float4* fp = (const float4*)(F2 + (size_t)d * KEXP);
    float4 f0 = fp[0], f1 = fp[1];
    acc[0] += wv * (double)f0.x; acc[1] += wv * (double)f0.y;
    acc[2] += wv * (double)f0.z; acc[3] += wv * (double)f0.w;
    acc[4] += wv * (double)f1.x; acc[5] += wv * (double)f1.y;
    acc[6] += wv * (double)f1.z; acc[7] += wv * (double)f1.w;
  }
  __shared__ double sacc[4][64][KEXP];
#pragma unroll
  for (int k = 0; k < KEXP; ++k) sacc[ds][hl][k] = acc[k];
  __syncthreads();
  if (t < 64) {
#pragma unroll
    for (int k = 0; k < KEXP; ++k) {
      double s = sacc[0][t][k] + sacc[1][t][k] + sacc[2][t][k] + sacc[3][t][k];
      Bp[((size_t)blockIdx.y * DDIM + h0 + t) * KEXP + k] = s;
    }
  }
}

// ---------------- B reduce: Bm[h,k] = sum_db Bp[db][h][k] ----------------
__global__ void k_Bred(const double* __restrict__ Bp, float* __restrict__ Bm) {
  int g = blockIdx.x * 256 + threadIdx.x;  // 2048*8
  double s = 0.0;
#pragma unroll 8
  for (int b = 0; b < 32; ++b) s += Bp[(size_t)b * DDIM * KEXP + g];
  Bm[g] = (float)s;
}

// ---------------- W [D,H] -> transposed fp16 Wth[h][d] ----------------
__global__ void k_wt(const float* __restrict__ W, _Float16* __restrict__ Wth) {
  __shared__ float tl[32][33];
  int hb = blockIdx.x * 32, db = blockIdx.y * 32;
  int tx = threadIdx.x, ty = threadIdx.y;  // (32,8)
#pragma unroll
  for (int r = 0; r < 4; ++r) {
    int dd = ty + r * 8;
    tl[dd][tx] = W[(size_t)(db + dd) * DDIM + hb + tx];
  }
  __syncthreads();
#pragma unroll
  for (int r = 0; r < 4; ++r) {
    int hh = ty + r * 8;
    Wth[(size_t)(hb + hh) * DDIM + db + tx] = (_Float16)tl[tx][hh];
  }
}

// ---------------- Mct[i][d] = fp16(R[(d-i)&2047]) ----------------
__global__ void k_mc(const float* __restrict__ Rext, _Float16* __restrict__ Mct) {
  int gid = blockIdx.x * 256 + threadIdx.x;
  int i  = gid >> 8;
  int j8 = (gid & 255) << 3;
  int base = (j8 - i) & 2047;
  f16x8 h8;
#pragma unroll
  for (int e = 0; e < 8; ++e) h8[e] = (_Float16)Rext[base + e];
  *(f16x8*)(Mct + (size_t)i * DDIM + j8) = h8;
}

// ---------------- x chunk f32 -> fp16 ----------------
__global__ void k_xh(const float* __restrict__ x, _Float16* __restrict__ xh, int n8) {
  int stride = gridDim.x * blockDim.x;
  for (int g = blockIdx.x * blockDim.x + threadIdx.x; g < n8; g += stride) {
    size_t o = (size_t)g * 8;
    float4 a = *(const float4*)(x + o);
    float4 b = *(const float4*)(x + o + 4);
    f16x8 h8;
    h8[0] = (_Float16)a.x; h8[1] = (_Float16)a.y;
    h8[2] = (_Float16)a.z; h8[3] = (_Float16)a.w;
    h8[4] = (_Float16)b.x; h8[5] = (_Float16)b.y;
    h8[6] = (_Float16)b.z; h8[7] = (_Float16)b.w;
    *(f16x8*)(xh + o) = h8;
  }
}

// ---------------- fp16 GEMM, BK=64, XOR-swizzled LDS ----------------
// C[m,n] = sum_k A[m,k]*B[n,k]
// EPI 0: per-row sum of squares -> Pn[bx][rowbase + m]   (norm path)
// EPI 1: Ct[n][m] = fp16(C[m,n])                          (A_t build)
template <int EPI>
__global__ __launch_bounds__(256, 2)
void k_gemm16(const _Float16* __restrict__ A, const _Float16* __restrict__ B,
              float* __restrict__ Pn, _Float16* __restrict__ Ct,
              int M, int N, int K, int rowbase, int Mtot) {
  __shared__ __align__(16) _Float16 sA[128 * 64];
  __shared__ __align__(16) _Float16 sB[128 * 64];
  __shared__ float sred[2][2][64];

  const int nbx = N >> 7;
  const int nwg = gridDim.x * gridDim.y;
  const int lin = blockIdx.y * gridDim.x + blockIdx.x;
  // m204 bijective XCD swizzle
  const int qq = nwg >> 3, rr = nwg & 7;
  const int xcd = lin & 7, pos = lin >> 3;
  const int swz = ((xcd < rr) ? xcd * (qq + 1) : rr * (qq + 1) + (xcd - rr) * qq) + pos;
  const int bx = swz % nbx, by = swz / nbx;

  const int tid = threadIdx.x;
  const int lane = tid & 63;
  const int wid = tid >> 6;
  const int wm = wid >> 1, wn = wid & 1;
  const int m0 = by * 128, n0 = bx * 128;
  const int fr = lane & 15, fq = lane >> 4;

  f32x4 acc[4][4] = {};

  for (int kt = 0; kt < K; kt += 64) {
#pragma unroll
    for (int p = 0; p < 4; ++p) {
      int s = p * 256 + tid;      // 16B slot in buffer
      int r = s >> 3, c = s & 7;  // row, slot-in-row
      int ks = (c ^ (r & 7)) << 3;  // inverse-swizzled global k (halves)
      gload16(A + (size_t)(m0 + r) * K + kt + ks, (char*)sA + (size_t)s * 16);
      gload16(B + (size_t)(n0 + r) * K + kt + ks, (char*)sB + (size_t)s * 16);
    }
    __syncthreads();
#pragma unroll
    for (int kk = 0; kk < 2; ++kk) {
      f16x8 av[4], bv[4];
      const int q = (kk << 2) + fq;
#pragma unroll
      for (int i = 0; i < 4; ++i) {
        const int Ra = wm * 64 + i * 16 + fr;
        const int Rb = wn * 64 + i * 16 + fr;
        av[i] = *(const f16x8*)((char*)sA + Ra * 128 + ((q ^ (Ra & 7)) << 4));
        bv[i] = *(const f16x8*)((char*)sB + Rb * 128 + ((q ^ (Rb & 7)) << 4));
      }
#pragma unroll
      for (int mi = 0; mi < 4; ++mi)
#pragma unroll
        for (int ni = 0; ni < 4; ++ni)
          acc[mi][ni] = __builtin_amdgcn_mfma_f32_16x16x32_f16(av[mi], bv[ni], acc[mi][ni], 0, 0, 0);
    }
    __syncthreads();
  }

  if (EPI == 0) {
    // per-row sum of squares over this block's 128 cols
#pragma unroll
    for (int mi = 0; mi < 4; ++mi)
#pragma unroll
      for (int j = 0; j < 4; ++j) {
        float s = 0.f;
#pragma unroll
        for (int ni = 0; ni < 4; ++ni) s += acc[mi][ni][j] * acc[mi][ni][j];
#pragma unroll
        for (int o = 1; o < 16; o <<= 1) s += __shfl_xor(s, o);
        if (fr == 0) sred[wm][wn][mi * 16 + fq * 4 + j] = s;
      }
    __syncthreads();
    if (tid < 128) {
      int wmm = tid >> 6, rl = tid & 63;
      float v = sred[wmm][0][rl] + sred[wmm][1][rl];
      Pn[(size_t)bx * NROWS + rowbase + m0 + wmm * 64 + rl] = v;
    }
  } else {
#pragma unroll
    for (int mi = 0; mi < 4; ++mi)
#pragma unroll
      for (int ni = 0; ni < 4; ++ni) {
        const int orow = n0 + wn * 64 + ni * 16 + fr;
        const int ocol = m0 + wm * 64 + mi * 16 + fq * 4;
        f16x4 h4;
#pragma unroll
        for (int j = 0; j < 4; ++j) h4[j] = (_Float16)acc[mi][ni][j];
        *(f16x4*)(Ct + (size_t)orow * Mtot + ocol) = h4;
      }
  }
}

// ---------------- numerator + norm + top2 + softmax ----------------
__global__ void k_scores(const float* __restrict__ x, const float* __restrict__ Bm,
                         const float* __restrict__ Pn, float* __restrict__ out,
                         int rowbase) {
  int wid = threadIdx.x >> 6, lane = threadIdx.x & 63;
  int r = rowbase + blockIdx.x * 4 + wid;
  const float* xr = x + (size_t)r * DDIM;
  double dk[KEXP] = {};
  for (int h = lane; h < DDIM; h += 64) {
    double xv = (double)xr[h];
    const float4* bp = (const float4*)(Bm + (size_t)h * KEXP);
    float4 b0 = bp[0], b1 = bp[1];
    dk[0] += xv * b0.x; dk[1] += xv * b0.y; dk[2] += xv * b0.z; dk[3] += xv * b0.w;
    dk[4] += xv * b1.x; dk[5] += xv * b1.y; dk[6] += xv * b1.z; dk[7] += xv * b1.w;
  }
#pragma unroll
  for (int o = 32; o; o >>= 1)
#pragma unroll
    for (int k = 0; k < KEXP; ++k) dk[k] += __shfl_down(dk[k], o);
  if (lane == 0) {
    double ns = 0.0;
#pragma unroll
    for (int b = 0; b < 16; ++b) ns += (double)Pn[(size_t)b * NROWS + r];
    double nn = sqrt(ns); if (nn < 1e-12) nn = 1e-12;
    float sc[KEXP];
#pragma unroll
    for (int k = 0; k < KEXP; ++k) sc[k] = (float)(dk[k] / nn);
    float v1 = -3.4e38f, v2 = -3.4e38f; int i1 = 0, i2 = 0;
#pragma unroll
    for (int k = 0; k < KEXP; ++k) {
      float v = sc[k];
      if (v > v1) { v2 = v1; i2 = i1; v1 = v; i1 = k; }
      else if (v > v2) { v2 = v; i2 = k; }
    }
    float e = expf(v2 - v1);
    float w1 = 1.0f / (1.0f + e);
    float w2 = e / (1.0f + e);
    out[(size_t)r * 2] = w1;
    out[(size_t)r * 2 + 1] = w2;
    out[IDX_OFF + (size_t)r * 2] = (float)i1;
    out[IDX_OFF + (size_t)r * 2 + 1] = (float)i2;
#pragma unroll
    for (int k = 0; k < KEXP; ++k) out[SCR_OFF + (size_t)r * 8 + k] = sc[k];
  }
}

extern "C" void kernel_launch(void* const* d_in, const int* in_sizes, int n_in,
                              void* d_out, int out_size, void* d_ws, size_t ws_size,
                              hipStream_t stream) {
  const float* x   = (const float*)d_in[0];
  const float* W   = (const float*)d_in[1];
  const float* lab = (const float*)d_in[2];
  const float* sig = (const float*)d_in[3];
  float* out = (float*)d_out;

  char* p = (char*)d_ws;
  auto alloc = [&](size_t bytes) {
    void* r = (void*)p;
    p += (bytes + 255) & ~(size_t)255;
    return r;
  };
  float* Lb   = (float*)alloc((size_t)KEXP * DDIM * 4);
  float* Eb   = (float*)alloc((size_t)KEXP * DDIM * 4);
  float* Rext = (float*)alloc((size_t)4112 * 4);
  float* F2   = (float*)alloc((size_t)DDIM * KEXP * 4);
  double* Bp  = (double*)alloc((size_t)32 * DDIM * KEXP * 8);
  float* Bm   = (float*)alloc((size_t)DDIM * KEXP * 4);
  _Float16* Wth = (_Float16*)alloc((size_t)DDIM * DDIM * 2);
  _Float16* Mct = (_Float16*)alloc((size_t)DDIM * DDIM * 2);
  _Float16* At  = (_Float16*)alloc((size_t)DDIM * DDIM * 2);
  float* Pn     = (float*)alloc((size_t)16 * NROWS * 4);
  size_t fixed = (size_t)(p - (char*)d_ws);

  int NC = NROWS;  // xh chunk rows
  while (NC > 2048 && fixed + (size_t)NC * DDIM * 2 + 4096 > ws_size) NC >>= 1;
  _Float16* Xh = (_Float16*)alloc((size_t)NC * DDIM * 2);

  k_norm<<<16, 256, 0, stream>>>(lab, sig, Lb, Eb);
  k_R<<<2048, 256, 0, stream>>>(Lb, Eb, Rext);
  k_F2<<<2048, 256, 0, stream>>>(Rext, Eb, F2);
  k_Bp<<<dim3(32, 32), 256, 0, stream>>>(W, F2, Bp);
  k_Bred<<<64, 256, 0, stream>>>(Bp, Bm);
  k_wt<<<dim3(64, 64), dim3(32, 8), 0, stream>>>(W, Wth);
  k_mc<<<2048, 256, 0, stream>>>(Rext, Mct);
  // At[i][h] = fp16( sum_d Wth[h,d] * Mct[i,d] )
  k_gemm16<1><<<dim3(16, 16), 256, 0, stream>>>(Wth, Mct, nullptr, At,
                                                DDIM, DDIM, DDIM, 0, DDIM);
  const int nchunks = NROWS / NC;
  for (int c = 0; c < nchunks; ++c) {
    const float* xc = x + (size_t)c * NC * DDIM;
    k_xh<<<1024, 256, 0, stream>>>(xc, Xh, NC * DDIM / 8);
    k_gemm16<0><<<dim3(16, NC / 128), 256, 0, stream>>>(Xh, At, Pn, nullptr,
                                                        NC, DDIM, DDIM, c * NC, DDIM);
    k_scores<<<NC / 4, 256, 0, stream>>>(x, Bm, Pn, out, c * NC);
  }
}